// Round 10
// baseline (43.133 us; speedup 1.0000x reference)
//
#include <hip/hip_runtime.h>

#define BB 256
#define SS 2048
#define FF 64
#define NBB 32

#define TPB 512            // threads per block (8 waves)
#define MT 4               // output timesteps per thread
#define OT (TPB*MT)        // 2048 = whole sequence per block
#define WUP 96             // speculative warm-up steps (validated r5-r9)
#define ROWS (OT+WUP)      // 2144 u rows in LDS
#define NGRP (TPB/16)      // 32 16-lane groups
#define RPG (ROWS/NGRP)    // 67 rows per group
#define NF2 (ROWS/2)       // 1072 float2 in u_lds

// 2*log2(e): folded into u so the chain needs only exp2
#define TWO_OVER_LN2 2.885390081777927f

// ---------------------------------------------------------------------------
// ONE kernel, ONE block per batch (256 blocks, 1/CU, 8 waves).
//  phase 1: cooperative projection of 2144 rows of X into LDS u (+ tf).
//           u never touches HBM; X duplication only 2144/2048 = 1.047x.
//  phase 2: thread j owns t0=j*4: 96 speculative warm steps (LDS float2
//           reads, 4-deep static rotating prefetch) -> 4 output steps ->
//           32-basis intensity head in-register -> 8 dword stores.
// Exact-start: threads with t0 < WUP hold r (cndmask, VALU pipe - off the
// trans bottleneck) until global t reaches 0, starting from true hx0.
// XCD swizzle: b = (bid&7)*32 + bid>>3 -> 32 consecutive b per XCD, so each
// 64-B [t][b] output line is written by blocks of a single XCD.
// ---------------------------------------------------------------------------

#define CSTEP(uu, kk) { \
    float z_ = fmaf(m2w, r, (uu)); \
    float rn_ = __builtin_amdgcn_rcpf(__builtin_amdgcn_exp2f(z_) + 1.0f); \
    r = ((kk) >= K0) ? rn_ : r; }

__global__ __launch_bounds__(TPB) void k_one(
    const float* __restrict__ X, const float* __restrict__ hx0,
    const float* __restrict__ W_ih, const float* __restrict__ b_ih,
    const float* __restrict__ W_hh, const float* __restrict__ b_hh,
    const float* __restrict__ W_h2p, const float* __restrict__ b_h2p,
    float* __restrict__ out_h, float* __restrict__ out_l)
{
    __shared__ __align__(16) float u_lds[ROWS];
    __shared__ __align__(16) float tf_lds[OT];
    __shared__ float4 cb[NBB];

    const int bid = blockIdx.x;
    const int b   = (bid & 7) * 32 + (bid >> 3);     // XCD-local batch packing

    if (threadIdx.x < NBB) {
        int jj = threadIdx.x;
        cb[jj] = make_float4(W_h2p[2*jj], W_h2p[2*jj+1], b_h2p[2*jj], b_h2p[2*jj+1]);
    }

    const float wp  = W_hh[0] * TWO_OVER_LN2;
    const float m2w = -2.0f * wp;

    // ---------------- phase 1: projection into LDS ----------------
    {
        const int l = threadIdx.x & 15;
        const int g = threadIdx.x >> 4;              // 0..31
        const float4 w = reinterpret_cast<const float4*>(W_ih)[l];
        const float bias = b_ih[0] + b_hh[0];
        const float* Xb = X + (size_t)b * SS * FF;
        #pragma unroll 4
        for (int it = 0; it < RPG; ++it) {           // 67 iters
            const int i = g + it * NGRP;             // LDS row
            const int t = i - WUP;                   // global timestep
            float pacc = 0.0f, vy = 0.0f;
            if (t >= 0) {                            // group-uniform predicate
                const float4 v = reinterpret_cast<const float4*>(
                    Xb + (size_t)t * FF)[l];
                pacc = v.x*w.x + v.y*w.y + v.z*w.z + v.w*w.w;
                vy = v.y;
            }
            pacc += __shfl_xor(pacc, 1);
            pacc += __shfl_xor(pacc, 2);
            pacc += __shfl_xor(pacc, 4);
            pacc += __shfl_xor(pacc, 8);
            if (l == 0) {
                u_lds[i] = (t >= 0) ? (TWO_OVER_LN2 * (pacc + bias) + wp) : 0.0f;
                if (i >= WUP) tf_lds[t] = vy;        // X[b,t,1]
            }
        }
    }
    __syncthreads();

    // ---------------- phase 2: private speculative chain ----------------
    const int j  = threadIdx.x;
    const int t0 = j * MT;

    float r; int K0;
    if (t0 < WUP) { r = 0.5f * (1.0f - hx0[b]); K0 = WUP - t0; }  // exact start
    else          { r = 0.5f;                   K0 = 0; }          // neutral

    const float2* U2 = reinterpret_cast<const float2*>(u_lds);
    const int jb = j * (MT/2);                      // = j*2, base float2 index
    float2 pf0 = U2[jb], pf1 = U2[jb+1], pf2 = U2[jb+2], pf3 = U2[jb+3];

    // 12 groups x 8 steps; each float2 used then refilled 8 steps ahead
    // (~240cy chain > ~120cy LDS latency). All buffer indexing static.
    #pragma unroll 1
    for (int grp = 0; grp < WUP/8; ++grp) {
        const int kb = grp * 8;
        const int rb = jb + grp*4 + 4;
        { const float2 c_ = pf0; CSTEP(c_.x, kb+0) CSTEP(c_.y, kb+1)
          int ri_ = rb + 0; if (ri_ > NF2-1) ri_ = NF2-1; pf0 = U2[ri_]; }
        { const float2 c_ = pf1; CSTEP(c_.x, kb+2) CSTEP(c_.y, kb+3)
          int ri_ = rb + 1; if (ri_ > NF2-1) ri_ = NF2-1; pf1 = U2[ri_]; }
        { const float2 c_ = pf2; CSTEP(c_.x, kb+4) CSTEP(c_.y, kb+5)
          int ri_ = rb + 2; if (ri_ > NF2-1) ri_ = NF2-1; pf2 = U2[ri_]; }
        { const float2 c_ = pf3; CSTEP(c_.x, kb+6) CSTEP(c_.y, kb+7)
          int ri_ = rb + 3; if (ri_ > NF2-1) ri_ = NF2-1; pf3 = U2[ri_]; }
    }

    // after the loop: pf0 = u[rows t0+96,97], pf1 = u[rows t0+98,99]
    float hx[MT];
    { float z = fmaf(m2w, r, pf0.x);
      r = __builtin_amdgcn_rcpf(__builtin_amdgcn_exp2f(z) + 1.0f);
      hx[0] = fmaf(-2.0f, r, 1.0f); }
    { float z = fmaf(m2w, r, pf0.y);
      r = __builtin_amdgcn_rcpf(__builtin_amdgcn_exp2f(z) + 1.0f);
      hx[1] = fmaf(-2.0f, r, 1.0f); }
    { float z = fmaf(m2w, r, pf1.x);
      r = __builtin_amdgcn_rcpf(__builtin_amdgcn_exp2f(z) + 1.0f);
      hx[2] = fmaf(-2.0f, r, 1.0f); }
    { float z = fmaf(m2w, r, pf1.y);
      r = __builtin_amdgcn_rcpf(__builtin_amdgcn_exp2f(z) + 1.0f);
      hx[3] = fmaf(-2.0f, r, 1.0f); }

    // ---------------- intensity head, in-register ----------------
    const float4 ttv = reinterpret_cast<const float4*>(tf_lds)[j];
    const float tt[MT] = { ttv.x, ttv.y, ttv.z, ttv.w };
    float s[MT] = { 0.0f, 0.0f, 0.0f, 0.0f };
    #pragma unroll 8
    for (int jj = 0; jj < NBB; ++jj) {
        const float4 c = cb[jj];                     // uniform LDS broadcast
        #pragma unroll
        for (int k = 0; k < MT; ++k)
            s[k] += fmaxf(fmaf(fmaf(hx[k], c.x, c.z), tt[k],
                               fmaf(hx[k], c.y, c.w)), 0.0f);
    }

    const size_t o0 = (size_t)t0 * BB + b;
    #pragma unroll
    for (int k = 0; k < MT; ++k) {
        out_h[o0 + (size_t)k * BB] = hx[k];
        float vv = s[k];
        float as = fabsf(vv);
        float e  = __builtin_amdgcn_exp2f(-as * 1.4426950408889634f);
        float lg = __builtin_amdgcn_logf(1.0f + e) * 0.6931471805599453f;
        out_l[o0 + (size_t)k * BB] = fmaxf(vv, 0.0f) + lg;
    }
}

// ---------------------------------------------------------------------------
extern "C" void kernel_launch(void* const* d_in, const int* in_sizes, int n_in,
                              void* d_out, int out_size, void* d_ws, size_t ws_size,
                              hipStream_t stream) {
    const float* X     = (const float*)d_in[0];
    const float* hx0   = (const float*)d_in[1];
    const float* W_ih  = (const float*)d_in[2];
    const float* b_ih  = (const float*)d_in[3];
    const float* W_hh  = (const float*)d_in[4];
    const float* b_hh  = (const float*)d_in[5];
    const float* W_h2p = (const float*)d_in[6];
    const float* b_h2p = (const float*)d_in[7];

    float* out_h = (float*)d_out;                 // hidden_states (S,B,1) [t][b]
    float* out_l = out_h + (size_t)SS * BB;       // intensity     (S,B)   [t][b]

    k_one<<<BB, TPB, 0, stream>>>(X, hx0, W_ih, b_ih, W_hh, b_hh,
                                  W_h2p, b_h2p, out_h, out_l);
}

// Round 11
// 32.043 us; speedup vs baseline: 1.3461x; 1.3461x over previous
//
#include <hip/hip_runtime.h>

#define BB 256
#define SS 2048
#define FF 64
#define NBB 32

#define TPB 512            // threads per block (8 waves)
#define MT 2               // output timesteps per thread
#define OT (TPB*MT)        // 1024 output t per block
#define WUP 64             // speculative warm-up steps (contraction >= e^-38)
#define ROWS (OT+WUP)      // 1088 u rows in LDS
#define NCHUNK (SS/OT)     // 2 t-chunks
#define NGRP (TPB/16)      // 32 16-lane groups
#define RPG (ROWS/NGRP)    // 34 rows per group
#define NF2 (ROWS/2)       // 544 float2 in u_lds

// 2*log2(e): folded into u so the chain needs only exp2
#define TWO_OVER_LN2 2.885390081777927f

// ---------------------------------------------------------------------------
// ONE kernel. block = (batch b, t-chunk of 1024 outputs). No cross-block sync.
// 512 blocks x 8 waves = 2 blocks/CU: one block's trans-bound phase 2
// overlaps the other's memory-bound phase 1 (round-10 lesson: 1 block/CU
// serializes the phases chip-wide and regresses 9 us).
//  phase 1: cooperative projection of 1088 rows of X into LDS u (+ tf).
//           u never round-trips HBM; X duplication 1088/1024 = 1.0625x.
//  phase 2: thread j: private 64-step speculative chain (LDS float2 reads,
//           4-deep static rotating prefetch) -> 2 output steps -> 32-basis
//           head in-register -> 4 dword stores.
// Chunk-0 threads with t0 < WUP start EXACT from hx0 (cndmask on the chain).
// XCD swizzle: 32 consecutive b per XCD so [t][b] output lines aggregate
// within one XCD's L2.
// ---------------------------------------------------------------------------

#define CSTEP_P(uu, kk) { \
    float z_ = fmaf(m2w, r, (uu)); \
    float rn_ = __builtin_amdgcn_rcpf(__builtin_amdgcn_exp2f(z_) + 1.0f); \
    r = ((kk) >= K0) ? rn_ : r; }

#define CSTEP_N(uu, kk) { \
    float z_ = fmaf(m2w, r, (uu)); \
    r = __builtin_amdgcn_rcpf(__builtin_amdgcn_exp2f(z_) + 1.0f); }

// 8 groups x 8 steps; each float2 pfX used then refilled 8 steps ahead
// (~240cy of chain > ~120cy LDS latency). All buffer indexing static.
// After the last group, pf0 = U2[j+WUP/2] = this thread's 2 output u values.
#define WARMLOOP(CS) \
    _Pragma("unroll 1") \
    for (int grp = 0; grp < WUP/8; ++grp) { \
        const int kb = grp * 8; \
        const int rb = j + grp*4 + 4; \
        { const float2 c_ = pf0; CS(c_.x, kb+0) CS(c_.y, kb+1) \
          int ri_ = rb + 0; if (ri_ > NF2-1) ri_ = NF2-1; pf0 = U2[ri_]; } \
        { const float2 c_ = pf1; CS(c_.x, kb+2) CS(c_.y, kb+3) \
          int ri_ = rb + 1; if (ri_ > NF2-1) ri_ = NF2-1; pf1 = U2[ri_]; } \
        { const float2 c_ = pf2; CS(c_.x, kb+4) CS(c_.y, kb+5) \
          int ri_ = rb + 2; if (ri_ > NF2-1) ri_ = NF2-1; pf2 = U2[ri_]; } \
        { const float2 c_ = pf3; CS(c_.x, kb+6) CS(c_.y, kb+7) \
          int ri_ = rb + 3; if (ri_ > NF2-1) ri_ = NF2-1; pf3 = U2[ri_]; } \
    }

__global__ __launch_bounds__(TPB) void k_one(
    const float* __restrict__ X, const float* __restrict__ hx0,
    const float* __restrict__ W_ih, const float* __restrict__ b_ih,
    const float* __restrict__ W_hh, const float* __restrict__ b_hh,
    const float* __restrict__ W_h2p, const float* __restrict__ b_h2p,
    float* __restrict__ out_h, float* __restrict__ out_l)
{
    __shared__ __align__(16) float u_lds[ROWS];
    __shared__ __align__(16) float tf_lds[OT];
    __shared__ float4 cb[NBB];

    // block decode with XCD swizzle: b in [xcd*32, xcd*32+32), 2 chunks each
    const int bid   = blockIdx.x;
    const int xcd   = bid & 7;
    const int qq    = bid >> 3;              // 0..63
    const int b     = xcd * 32 + (qq & 31);
    const int chunk = qq >> 5;               // 0..1
    const int T0    = chunk * OT;

    if (threadIdx.x < NBB) {
        int jj = threadIdx.x;
        cb[jj] = make_float4(W_h2p[2*jj], W_h2p[2*jj+1], b_h2p[2*jj], b_h2p[2*jj+1]);
    }

    const float wp  = W_hh[0] * TWO_OVER_LN2;
    const float m2w = -2.0f * wp;

    // ---------------- phase 1: projection into LDS ----------------
    {
        const int l = threadIdx.x & 15;
        const int g = threadIdx.x >> 4;              // 0..31
        const float4 w = reinterpret_cast<const float4*>(W_ih)[l];
        const float bias = b_ih[0] + b_hh[0];
        const float* Xb = X + (size_t)b * SS * FF;
        #pragma unroll 4
        for (int it = 0; it < RPG; ++it) {           // 34 iters
            const int i = g + it * NGRP;             // LDS row
            const int t = T0 - WUP + i;              // global timestep
            float pacc = 0.0f, vy = 0.0f;
            if (t >= 0) {                            // group-uniform predicate
                const float4 v = reinterpret_cast<const float4*>(
                    Xb + (size_t)t * FF)[l];
                pacc = v.x*w.x + v.y*w.y + v.z*w.z + v.w*w.w;
                vy = v.y;
            }
            pacc += __shfl_xor(pacc, 1);
            pacc += __shfl_xor(pacc, 2);
            pacc += __shfl_xor(pacc, 4);
            pacc += __shfl_xor(pacc, 8);
            if (l == 0) {
                u_lds[i] = (t >= 0) ? (TWO_OVER_LN2 * (pacc + bias) + wp) : 0.0f;
                if (i >= WUP) tf_lds[i - WUP] = vy;  // X[b,t,1]
            }
        }
    }
    __syncthreads();

    // ---------------- phase 2: private speculative chain ----------------
    const int j  = threadIdx.x;
    const int t0 = j * MT;                           // local output t (even)

    float r; int K0;
    if (chunk == 0 && t0 < WUP) { r = 0.5f * (1.0f - hx0[b]); K0 = WUP - t0; }
    else                        { r = 0.5f;          K0 = 0; }

    const float2* U2 = reinterpret_cast<const float2*>(u_lds);
    float2 pf0 = U2[j], pf1 = U2[j+1], pf2 = U2[j+2], pf3 = U2[j+3];

    if (chunk == 0) { WARMLOOP(CSTEP_P) }            // uniform branch per block
    else            { WARMLOOP(CSTEP_N) }

    // after the loop pf0 = u[t0+WUP], u[t0+WUP+1] — the two output steps
    float hxa, hxb;
    { float z = fmaf(m2w, r, pf0.x);
      r = __builtin_amdgcn_rcpf(__builtin_amdgcn_exp2f(z) + 1.0f);
      hxa = fmaf(-2.0f, r, 1.0f); }
    { float z = fmaf(m2w, r, pf0.y);
      r = __builtin_amdgcn_rcpf(__builtin_amdgcn_exp2f(z) + 1.0f);
      hxb = fmaf(-2.0f, r, 1.0f); }

    // ---------------- intensity head, in-register ----------------
    const float2 ttv = reinterpret_cast<const float2*>(tf_lds)[j];
    float s0 = 0.0f, s1 = 0.0f;
    #pragma unroll 8
    for (int jj = 0; jj < NBB; ++jj) {
        const float4 c = cb[jj];                     // uniform LDS broadcast
        s0 += fmaxf(fmaf(fmaf(hxa, c.x, c.z), ttv.x, fmaf(hxa, c.y, c.w)), 0.0f);
        s1 += fmaxf(fmaf(fmaf(hxb, c.x, c.z), ttv.y, fmaf(hxb, c.y, c.w)), 0.0f);
    }

    const size_t o0 = (size_t)(T0 + t0) * BB + b;
    out_h[o0]      = hxa;
    out_h[o0 + BB] = hxb;
    { float as = fabsf(s0);
      float e  = __builtin_amdgcn_exp2f(-as * 1.4426950408889634f);
      float lg = __builtin_amdgcn_logf(1.0f + e) * 0.6931471805599453f;
      out_l[o0] = fmaxf(s0, 0.0f) + lg; }
    { float as = fabsf(s1);
      float e  = __builtin_amdgcn_exp2f(-as * 1.4426950408889634f);
      float lg = __builtin_amdgcn_logf(1.0f + e) * 0.6931471805599453f;
      out_l[o0 + BB] = fmaxf(s1, 0.0f) + lg; }
}

// ---------------------------------------------------------------------------
extern "C" void kernel_launch(void* const* d_in, const int* in_sizes, int n_in,
                              void* d_out, int out_size, void* d_ws, size_t ws_size,
                              hipStream_t stream) {
    const float* X     = (const float*)d_in[0];
    const float* hx0   = (const float*)d_in[1];
    const float* W_ih  = (const float*)d_in[2];
    const float* b_ih  = (const float*)d_in[3];
    const float* W_hh  = (const float*)d_in[4];
    const float* b_hh  = (const float*)d_in[5];
    const float* W_h2p = (const float*)d_in[6];
    const float* b_h2p = (const float*)d_in[7];

    float* out_h = (float*)d_out;                 // hidden_states (S,B,1) [t][b]
    float* out_l = out_h + (size_t)SS * BB;       // intensity     (S,B)   [t][b]

    k_one<<<NCHUNK * BB, TPB, 0, stream>>>(X, hx0, W_ih, b_ih, W_hh, b_hh,
                                           W_h2p, b_h2p, out_h, out_l);
}

// Round 12
// 31.169 us; speedup vs baseline: 1.3838x; 1.0280x over previous
//
#include <hip/hip_runtime.h>

#define BB 256
#define SS 2048
#define FF 64
#define NBB 32

#define TPB 256            // threads per block (4 waves)
#define MT 2               // output timesteps per thread
#define OT (TPB*MT)        // 512 output t per block
#define WUP 32             // speculative warm-up steps (contraction ~e^-30)
#define ROWS (OT+WUP)      // 544 u rows in LDS
#define NCHUNK (SS/OT)     // 4 t-chunks
#define NGRP (TPB/16)      // 16 16-lane groups
#define RPG (ROWS/NGRP)    // 34 rows per group
#define NF2 (ROWS/2)       // 272 float2 in u_lds

// 2*log2(e): folded into u so the chain needs only exp2
#define TWO_OVER_LN2 2.885390081777927f

// ---------------------------------------------------------------------------
// ONE kernel. block = (batch b, t-chunk of 512 outputs). No cross-block sync.
// 1024 blocks x 4 waves = 4 blocks/CU (16 waves/CU): finer phase staggering
// than r11's 2x8 — one block's BW-bound phase 1 covers another's trans-bound
// phase 2; barrier scope halves; chain len halves. Fetch UNCHANGED (544/512
// = 1.0625x duplication, same as r11's 1088/1024).
//  phase 1: cooperative projection of 544 rows of X into LDS u (+ tf).
//  phase 2: thread j: private 32-step speculative chain (LDS float2 reads,
//           4-deep static rotating prefetch) -> 2 output steps -> 32-basis
//           head in-register -> 4 dword stores.
// Chunk-0 threads with t0 < WUP start EXACT from hx0 (cndmask on the chain).
// XCD swizzle: 32 consecutive b per XCD so [t][b] output lines aggregate
// within one XCD's L2.
// ---------------------------------------------------------------------------

#define CSTEP_P(uu, kk) { \
    float z_ = fmaf(m2w, r, (uu)); \
    float rn_ = __builtin_amdgcn_rcpf(__builtin_amdgcn_exp2f(z_) + 1.0f); \
    r = ((kk) >= K0) ? rn_ : r; }

#define CSTEP_N(uu, kk) { \
    float z_ = fmaf(m2w, r, (uu)); \
    r = __builtin_amdgcn_rcpf(__builtin_amdgcn_exp2f(z_) + 1.0f); }

// 4 groups x 8 steps; each float2 pfX used then refilled 8 steps ahead
// (~240cy of chain > ~120cy LDS latency). All buffer indexing static.
// After the last group, pf0 = U2[j+WUP/2] = this thread's 2 output u values.
#define WARMLOOP(CS) \
    _Pragma("unroll 1") \
    for (int grp = 0; grp < WUP/8; ++grp) { \
        const int kb = grp * 8; \
        const int rb = j + grp*4 + 4; \
        { const float2 c_ = pf0; CS(c_.x, kb+0) CS(c_.y, kb+1) \
          int ri_ = rb + 0; if (ri_ > NF2-1) ri_ = NF2-1; pf0 = U2[ri_]; } \
        { const float2 c_ = pf1; CS(c_.x, kb+2) CS(c_.y, kb+3) \
          int ri_ = rb + 1; if (ri_ > NF2-1) ri_ = NF2-1; pf1 = U2[ri_]; } \
        { const float2 c_ = pf2; CS(c_.x, kb+4) CS(c_.y, kb+5) \
          int ri_ = rb + 2; if (ri_ > NF2-1) ri_ = NF2-1; pf2 = U2[ri_]; } \
        { const float2 c_ = pf3; CS(c_.x, kb+6) CS(c_.y, kb+7) \
          int ri_ = rb + 3; if (ri_ > NF2-1) ri_ = NF2-1; pf3 = U2[ri_]; } \
    }

__global__ __launch_bounds__(TPB) void k_one(
    const float* __restrict__ X, const float* __restrict__ hx0,
    const float* __restrict__ W_ih, const float* __restrict__ b_ih,
    const float* __restrict__ W_hh, const float* __restrict__ b_hh,
    const float* __restrict__ W_h2p, const float* __restrict__ b_h2p,
    float* __restrict__ out_h, float* __restrict__ out_l)
{
    __shared__ __align__(16) float u_lds[ROWS];
    __shared__ __align__(16) float tf_lds[OT];
    __shared__ float4 cb[NBB];

    // block decode with XCD swizzle: b in [xcd*32, xcd*32+32), 4 chunks each
    const int bid   = blockIdx.x;
    const int xcd   = bid & 7;
    const int qq    = bid >> 3;              // 0..127
    const int b     = xcd * 32 + (qq & 31);
    const int chunk = qq >> 5;               // 0..3
    const int T0    = chunk * OT;

    if (threadIdx.x < NBB) {
        int jj = threadIdx.x;
        cb[jj] = make_float4(W_h2p[2*jj], W_h2p[2*jj+1], b_h2p[2*jj], b_h2p[2*jj+1]);
    }

    const float wp  = W_hh[0] * TWO_OVER_LN2;
    const float m2w = -2.0f * wp;

    // ---------------- phase 1: projection into LDS ----------------
    {
        const int l = threadIdx.x & 15;
        const int g = threadIdx.x >> 4;              // 0..15
        const float4 w = reinterpret_cast<const float4*>(W_ih)[l];
        const float bias = b_ih[0] + b_hh[0];
        const float* Xb = X + (size_t)b * SS * FF;
        #pragma unroll 4
        for (int it = 0; it < RPG; ++it) {           // 34 iters
            const int i = g + it * NGRP;             // LDS row
            const int t = T0 - WUP + i;              // global timestep
            float pacc = 0.0f, vy = 0.0f;
            if (t >= 0) {                            // group-uniform predicate
                const float4 v = reinterpret_cast<const float4*>(
                    Xb + (size_t)t * FF)[l];
                pacc = v.x*w.x + v.y*w.y + v.z*w.z + v.w*w.w;
                vy = v.y;
            }
            pacc += __shfl_xor(pacc, 1);
            pacc += __shfl_xor(pacc, 2);
            pacc += __shfl_xor(pacc, 4);
            pacc += __shfl_xor(pacc, 8);
            if (l == 0) {
                u_lds[i] = (t >= 0) ? (TWO_OVER_LN2 * (pacc + bias) + wp) : 0.0f;
                if (i >= WUP) tf_lds[i - WUP] = vy;  // X[b,t,1]
            }
        }
    }
    __syncthreads();

    // ---------------- phase 2: private speculative chain ----------------
    const int j  = threadIdx.x;
    const int t0 = j * MT;                           // local output t (even)

    float r; int K0;
    if (chunk == 0 && t0 < WUP) { r = 0.5f * (1.0f - hx0[b]); K0 = WUP - t0; }
    else                        { r = 0.5f;          K0 = 0; }

    const float2* U2 = reinterpret_cast<const float2*>(u_lds);
    float2 pf0 = U2[j], pf1 = U2[j+1], pf2 = U2[j+2], pf3 = U2[j+3];

    if (chunk == 0) { WARMLOOP(CSTEP_P) }            // uniform branch per block
    else            { WARMLOOP(CSTEP_N) }

    // after the loop pf0 = u[t0+WUP], u[t0+WUP+1] — the two output steps
    float hxa, hxb;
    { float z = fmaf(m2w, r, pf0.x);
      r = __builtin_amdgcn_rcpf(__builtin_amdgcn_exp2f(z) + 1.0f);
      hxa = fmaf(-2.0f, r, 1.0f); }
    { float z = fmaf(m2w, r, pf0.y);
      r = __builtin_amdgcn_rcpf(__builtin_amdgcn_exp2f(z) + 1.0f);
      hxb = fmaf(-2.0f, r, 1.0f); }

    // ---------------- intensity head, in-register ----------------
    const float2 ttv = reinterpret_cast<const float2*>(tf_lds)[j];
    float s0 = 0.0f, s1 = 0.0f;
    #pragma unroll 8
    for (int jj = 0; jj < NBB; ++jj) {
        const float4 c = cb[jj];                     // uniform LDS broadcast
        s0 += fmaxf(fmaf(fmaf(hxa, c.x, c.z), ttv.x, fmaf(hxa, c.y, c.w)), 0.0f);
        s1 += fmaxf(fmaf(fmaf(hxb, c.x, c.z), ttv.y, fmaf(hxb, c.y, c.w)), 0.0f);
    }

    const size_t o0 = (size_t)(T0 + t0) * BB + b;
    out_h[o0]      = hxa;
    out_h[o0 + BB] = hxb;
    { float as = fabsf(s0);
      float e  = __builtin_amdgcn_exp2f(-as * 1.4426950408889634f);
      float lg = __builtin_amdgcn_logf(1.0f + e) * 0.6931471805599453f;
      out_l[o0] = fmaxf(s0, 0.0f) + lg; }
    { float as = fabsf(s1);
      float e  = __builtin_amdgcn_exp2f(-as * 1.4426950408889634f);
      float lg = __builtin_amdgcn_logf(1.0f + e) * 0.6931471805599453f;
      out_l[o0 + BB] = fmaxf(s1, 0.0f) + lg; }
}

// ---------------------------------------------------------------------------
extern "C" void kernel_launch(void* const* d_in, const int* in_sizes, int n_in,
                              void* d_out, int out_size, void* d_ws, size_t ws_size,
                              hipStream_t stream) {
    const float* X     = (const float*)d_in[0];
    const float* hx0   = (const float*)d_in[1];
    const float* W_ih  = (const float*)d_in[2];
    const float* b_ih  = (const float*)d_in[3];
    const float* W_hh  = (const float*)d_in[4];
    const float* b_hh  = (const float*)d_in[5];
    const float* W_h2p = (const float*)d_in[6];
    const float* b_h2p = (const float*)d_in[7];

    float* out_h = (float*)d_out;                 // hidden_states (S,B,1) [t][b]
    float* out_l = out_h + (size_t)SS * BB;       // intensity     (S,B)   [t][b]

    k_one<<<NCHUNK * BB, TPB, 0, stream>>>(X, hx0, W_ih, b_ih, W_hh, b_hh,
                                           W_h2p, b_h2p, out_h, out_l);
}